// Round 16
// baseline (494.793 us; speedup 1.0000x reference)
//
#include <hip/hip_runtime.h>

#define N_NODES 100000
#define EDGES   1600000
#define SCAN_NB ((N_NODES + 511) / 512)   // 196 scan blocks
#define GRID_HEAVY 2048

// ---- bf16 helpers ----------------------------------------------------------
__device__ __forceinline__ unsigned pack_bf16(float a, float b) {
    unsigned ua = (__float_as_uint(a) + 0x8000u) >> 16;
    unsigned ub = (__float_as_uint(b) + 0x8000u) & 0xffff0000u;
    return ub | ua;
}
__device__ __forceinline__ float bflo(unsigned p) { return __uint_as_float(p << 16); }
__device__ __forceinline__ float bfhi(unsigned p) { return __uint_as_float(p & 0xffff0000u); }
__device__ __forceinline__ float bf2f(unsigned short u) { return __uint_as_float(((unsigned)u) << 16); }
__device__ __forceinline__ unsigned short f2bf(float x) { return (unsigned short)((__float_as_uint(x) + 0x8000u) >> 16); }

// within-wave LDS producer->consumer fence: waves are independent, so no
// __syncthreads needed; lgkmcnt(0) + memory clobber orders ds_write/ds_read.
#define WAVE_FENCE() asm volatile("s_waitcnt lgkmcnt(0)" ::: "memory")

// ---------------- prep: x -> bf16 copy  +  dst histogram (fused) ------------
__global__ __launch_bounds__(256) void prep_kernel(
    const float* __restrict__ x, const int* __restrict__ ei,
    unsigned short* __restrict__ xb, int* __restrict__ cnt)
{
    int t = blockIdx.x * 256 + threadIdx.x;
    if (t < N_NODES * 32) xb[t] = f2bf(x[t]);
    if (t < EDGES) atomicAdd(&cnt[ei[EDGES + t]], 1);
}

// ---------------- exclusive scan over cnt[N] (3 kernels) -------------------
__global__ __launch_bounds__(512) void scan1_kernel(
    const int* __restrict__ cnt, int* __restrict__ part, int* __restrict__ bsum)
{
    __shared__ int s[512];
    int tid = threadIdx.x;
    int gid = blockIdx.x * 512 + tid;
    int v = (gid < N_NODES) ? cnt[gid] : 0;
    s[tid] = v;
    __syncthreads();
    for (int off = 1; off < 512; off <<= 1) {
        int t = (tid >= off) ? s[tid - off] : 0;
        __syncthreads();
        s[tid] += t;
        __syncthreads();
    }
    if (gid < N_NODES) part[gid] = s[tid] - v;
    if (tid == 511) bsum[blockIdx.x] = s[511];
}

__global__ __launch_bounds__(256) void scan2_kernel(
    const int* __restrict__ bsum, int* __restrict__ bsumx)
{
    __shared__ int s[256];
    int tid = threadIdx.x;
    int v = (tid < SCAN_NB) ? bsum[tid] : 0;
    s[tid] = v;
    __syncthreads();
    for (int off = 1; off < 256; off <<= 1) {
        int t = (tid >= off) ? s[tid - off] : 0;
        __syncthreads();
        s[tid] += t;
        __syncthreads();
    }
    bsumx[tid] = s[tid] - v;
}

__global__ __launch_bounds__(512) void scan3_kernel(
    const int* __restrict__ part, const int* __restrict__ bsumx,
    int* __restrict__ offs, int* __restrict__ cursor)
{
    int gid = blockIdx.x * 512 + threadIdx.x;
    if (gid < N_NODES) {
        int o = part[gid] + bsumx[blockIdx.x];
        offs[gid] = o;
        cursor[gid] = o;
    }
    if (gid == 0) offs[N_NODES] = EDGES;
}

// ---------------- CSR fill: bucket[pos] = (src, weight) --------------------
__global__ __launch_bounds__(256) void fill_kernel(
    const int* __restrict__ ei, const float* __restrict__ ew,
    int* __restrict__ cursor, uint2* __restrict__ bucket)
{
    int e = blockIdx.x * 256 + threadIdx.x;
    if (e >= EDGES) return;
    int d = ei[EDGES + e];
    int pos = atomicAdd(&cursor[d], 1);
    uint2 slot;
    slot.x = (unsigned)ei[e];
    slot.y = __float_as_uint(ew[e]);
    bucket[pos] = slot;
}

// ------- layer 1: barrier-free, 1 node/wave, 2 edges per wave-load ---------
__global__ __launch_bounds__(256, 6) void agg_dense1_kernel(
    const float* __restrict__ x, const unsigned short* __restrict__ xb,
    const uint2* __restrict__ bucket, const int* __restrict__ offs,
    const float* __restrict__ W_rel, const float* __restrict__ b_rel,
    const float* __restrict__ W_root, unsigned short* __restrict__ h1b)
{
    __shared__ unsigned pkrel[16][64];    // transposed packed: pk[k][h]
    __shared__ unsigned pkroot[16][64];
    __shared__ float sb[64];
    __shared__ __align__(16) float accr[4][32];
    __shared__ __align__(16) float xr[4][32];
    int tid = threadIdx.x;
    for (int i = tid; i < 16 * 64; i += 256) {
        int k = i >> 6, h = i & 63;
        pkrel[k][h]  = pack_bf16(W_rel[h * 32 + 2 * k],  W_rel[h * 32 + 2 * k + 1]);
        pkroot[k][h] = pack_bf16(W_root[h * 32 + 2 * k], W_root[h * 32 + 2 * k + 1]);
    }
    if (tid < 64) sb[tid] = b_rel[tid];
    __syncthreads();          // weights visible; ONLY barrier in the kernel

    int w = tid >> 6, lane = tid & 63;
    int sub = lane >> 5, f = lane & 31;
    int wid = blockIdx.x * 4 + w;

    for (int node = wid; node < N_NODES; node += GRID_HEAVY * 4) {
        // phase A: gather (2 edges per wave-load), root row load
        float acc = 0.f;
        if (sub == 0) xr[w][f] = x[(size_t)node * 32 + f];
        int o0 = __builtin_amdgcn_readfirstlane(offs[node]);
        int o1 = __builtin_amdgcn_readfirstlane(offs[node + 1]);
        int j = o0;
        for (; j + 8 <= o1; j += 8) {
            uint2 b0 = bucket[j + 0 + sub], b1 = bucket[j + 2 + sub];
            uint2 b2 = bucket[j + 4 + sub], b3 = bucket[j + 6 + sub];
            float v0 = bf2f(xb[(size_t)b0.x * 32 + f]);
            float v1 = bf2f(xb[(size_t)b1.x * 32 + f]);
            float v2 = bf2f(xb[(size_t)b2.x * 32 + f]);
            float v3 = bf2f(xb[(size_t)b3.x * 32 + f]);
            acc += v0 * __uint_as_float(b0.y) + v1 * __uint_as_float(b1.y)
                 + v2 * __uint_as_float(b2.y) + v3 * __uint_as_float(b3.y);
        }
        for (; j + 2 <= o1; j += 2) {
            uint2 b = bucket[j + sub];
            acc += bf2f(xb[(size_t)b.x * 32 + f]) * __uint_as_float(b.y);
        }
        if (j + sub < o1) {
            uint2 b = bucket[j + sub];
            acc += bf2f(xb[(size_t)b.x * 32 + f]) * __uint_as_float(b.y);
        }
        acc += __shfl_xor(acc, 32);       // combine the two half-wave partials
        if (sub == 0) accr[w][f] = acc;
        WAVE_FENCE();
        // phase B: h = lane; uniform float2 broadcasts + lane-consecutive weights
        {
            const float2* ap = (const float2*)accr[w];
            const float2* xp = (const float2*)xr[w];
            float sum = sb[lane];
            #pragma unroll
            for (int k = 0; k < 16; ++k) {
                float2 a = ap[k], xv = xp[k];
                unsigned pr = pkrel[k][lane], po = pkroot[k][lane];
                sum += a.x * bflo(pr) + a.y * bfhi(pr)
                     + xv.x * bflo(po) + xv.y * bfhi(po);
            }
            h1b[(size_t)node * 64 + lane] = f2bf(fmaxf(sum, 0.f));
        }
        WAVE_FENCE();         // reads done before next iteration overwrites
    }
}

// ------- layer 2: barrier-free, 1 node/wave, dense + fc --------------------
__global__ __launch_bounds__(256, 6) void agg_dense2_kernel(
    const unsigned short* __restrict__ h1b, const uint2* __restrict__ bucket,
    const int* __restrict__ offs,
    const float* __restrict__ W_rel, const float* __restrict__ b_rel,
    const float* __restrict__ W_root,
    const float* __restrict__ fc_w, const float* __restrict__ fc_b,
    float* __restrict__ out)
{
    __shared__ unsigned pkrel[32][64];    // transposed packed: pk[k][h]
    __shared__ unsigned pkroot[32][64];
    __shared__ unsigned pkfc[32][10];
    __shared__ float sb[64], sfb[10];
    __shared__ __align__(16) float accr[4][64];
    __shared__ __align__(16) float hvr[4][64];
    __shared__ __align__(16) float sh2r[4][64];
    int tid = threadIdx.x;
    for (int i = tid; i < 32 * 64; i += 256) {
        int k = i >> 6, h = i & 63;
        pkrel[k][h]  = pack_bf16(W_rel[h * 64 + 2 * k],  W_rel[h * 64 + 2 * k + 1]);
        pkroot[k][h] = pack_bf16(W_root[h * 64 + 2 * k], W_root[h * 64 + 2 * k + 1]);
    }
    for (int i = tid; i < 32 * 10; i += 256) {
        int k = i % 32, c = i / 32;
        pkfc[k][c] = pack_bf16(fc_w[c * 64 + 2 * k], fc_w[c * 64 + 2 * k + 1]);
    }
    if (tid < 64) sb[tid] = b_rel[tid];
    if (tid < 10) sfb[tid] = fc_b[tid];
    __syncthreads();          // ONLY barrier

    int w = tid >> 6, lane = tid & 63;
    int wid = blockIdx.x * 4 + w;

    for (int node = wid; node < N_NODES; node += GRID_HEAVY * 4) {
        // phase A: gather, 8-deep MLP, SGPR bounds
        float acc = 0.f;
        float hv = bf2f(h1b[(size_t)node * 64 + lane]);
        int o0 = __builtin_amdgcn_readfirstlane(offs[node]);
        int o1 = __builtin_amdgcn_readfirstlane(offs[node + 1]);
        int j = o0;
        for (; j + 8 <= o1; j += 8) {
            uint2 s0 = bucket[j + 0], s1 = bucket[j + 1];
            uint2 s2 = bucket[j + 2], s3 = bucket[j + 3];
            uint2 s4 = bucket[j + 4], s5 = bucket[j + 5];
            uint2 s6 = bucket[j + 6], s7 = bucket[j + 7];
            float v0 = bf2f(h1b[(size_t)s0.x * 64 + lane]);
            float v1 = bf2f(h1b[(size_t)s1.x * 64 + lane]);
            float v2 = bf2f(h1b[(size_t)s2.x * 64 + lane]);
            float v3 = bf2f(h1b[(size_t)s3.x * 64 + lane]);
            float v4 = bf2f(h1b[(size_t)s4.x * 64 + lane]);
            float v5 = bf2f(h1b[(size_t)s5.x * 64 + lane]);
            float v6 = bf2f(h1b[(size_t)s6.x * 64 + lane]);
            float v7 = bf2f(h1b[(size_t)s7.x * 64 + lane]);
            acc += v0 * __uint_as_float(s0.y) + v1 * __uint_as_float(s1.y)
                 + v2 * __uint_as_float(s2.y) + v3 * __uint_as_float(s3.y)
                 + v4 * __uint_as_float(s4.y) + v5 * __uint_as_float(s5.y)
                 + v6 * __uint_as_float(s6.y) + v7 * __uint_as_float(s7.y);
        }
        for (; j + 4 <= o1; j += 4) {
            uint2 s0 = bucket[j + 0], s1 = bucket[j + 1];
            uint2 s2 = bucket[j + 2], s3 = bucket[j + 3];
            float v0 = bf2f(h1b[(size_t)s0.x * 64 + lane]);
            float v1 = bf2f(h1b[(size_t)s1.x * 64 + lane]);
            float v2 = bf2f(h1b[(size_t)s2.x * 64 + lane]);
            float v3 = bf2f(h1b[(size_t)s3.x * 64 + lane]);
            acc += v0 * __uint_as_float(s0.y) + v1 * __uint_as_float(s1.y)
                 + v2 * __uint_as_float(s2.y) + v3 * __uint_as_float(s3.y);
        }
        for (; j < o1; ++j) {
            uint2 s = bucket[j];
            acc += bf2f(h1b[(size_t)s.x * 64 + lane]) * __uint_as_float(s.y);
        }
        accr[w][lane] = acc;
        hvr[w][lane] = hv;
        WAVE_FENCE();
        // phase B: relu dense, h = lane
        {
            const float2* ap = (const float2*)accr[w];
            const float2* hp = (const float2*)hvr[w];
            float sum = sb[lane];
            #pragma unroll
            for (int k = 0; k < 32; ++k) {
                float2 a = ap[k], h2 = hp[k];
                unsigned pr = pkrel[k][lane], po = pkroot[k][lane];
                sum += a.x * bflo(pr) + a.y * bfhi(pr)
                     + h2.x * bflo(po) + h2.y * bfhi(po);
            }
            sh2r[w][lane] = fmaxf(sum, 0.f);
        }
        WAVE_FENCE();
        // phase C: fc on 10 lanes (uniform sh2 broadcasts)
        if (lane < 10) {
            const float2* sp = (const float2*)sh2r[w];
            float o = sfb[lane];
            #pragma unroll
            for (int k = 0; k < 32; ++k) {
                float2 s2 = sp[k];
                unsigned pc = pkfc[k][lane];
                o += s2.x * bflo(pc) + s2.y * bfhi(pc);
            }
            out[(size_t)node * 10 + lane] = o;
        }
        WAVE_FENCE();         // sh2r reads done before next iteration writes
    }
}

extern "C" void kernel_launch(void* const* d_in, const int* in_sizes, int n_in,
                              void* d_out, int out_size, void* d_ws, size_t ws_size,
                              hipStream_t stream) {
    const float* x       = (const float*)d_in[0];
    const int*   ei      = (const int*)d_in[1];     // [2, E] int32
    const float* ew      = (const float*)d_in[2];
    const float* W1_rel  = (const float*)d_in[3];
    const float* b1_rel  = (const float*)d_in[4];
    const float* W1_root = (const float*)d_in[5];
    const float* W2_rel  = (const float*)d_in[6];
    const float* b2_rel  = (const float*)d_in[7];
    const float* W2_root = (const float*)d_in[8];
    const float* fc_w    = (const float*)d_in[9];
    const float* fc_b    = (const float*)d_in[10];
    float* out = (float*)d_out;

    // workspace layout (~34 MB)
    uint2* bucket       = (uint2*)d_ws;                          // E (12.8 MB)
    unsigned short* h1b = (unsigned short*)(bucket + EDGES);     // N*64 bf16 (12.8 MB)
    unsigned short* xb  = h1b + (size_t)N_NODES * 64;            // N*32 bf16 (6.4 MB)
    int*   cnt    = (int*)(xb + (size_t)N_NODES * 32);           // N
    int*   part   = cnt + N_NODES;                               // N
    int*   offs   = part + N_NODES;                              // N+1
    int*   cursor = offs + N_NODES + 1;                          // N
    int*   bsum   = cursor + N_NODES;                            // 256
    int*   bsumx  = bsum + 256;                                  // 256

    hipMemsetAsync(cnt, 0, (size_t)N_NODES * sizeof(int), stream);

    prep_kernel<<<(N_NODES * 32 + 255) / 256, 256, 0, stream>>>(x, ei, xb, cnt);
    scan1_kernel<<<SCAN_NB, 512, 0, stream>>>(cnt, part, bsum);
    scan2_kernel<<<1, 256, 0, stream>>>(bsum, bsumx);
    scan3_kernel<<<SCAN_NB, 512, 0, stream>>>(part, bsumx, offs, cursor);
    fill_kernel<<<(EDGES + 255) / 256, 256, 0, stream>>>(ei, ew, cursor, bucket);

    agg_dense1_kernel<<<GRID_HEAVY, 256, 0, stream>>>(
        x, xb, bucket, offs, W1_rel, b1_rel, W1_root, h1b);
    agg_dense2_kernel<<<GRID_HEAVY, 256, 0, stream>>>(
        h1b, bucket, offs, W2_rel, b2_rel, W2_root, fc_w, fc_b, out);
}